// Round 1
// baseline (32.683 us; speedup 1.0000x reference)
//
#include <hip/hip_runtime.h>
#include <math.h>

#define HW2   196      // 14*14
#define IMG   224
#define IMG2  (224*224)

// ---------------- K1: 16x16 patch means -> resized[B*196] ----------------
// One wave (64 lanes) per patch: lane = row*4 + c4, each lane loads float4.
__global__ __launch_bounds__(256) void k_patch_mean(const float* __restrict__ in,
                                                    float* __restrict__ resized,
                                                    int npair) {
    int wid  = threadIdx.x >> 6;
    int lane = threadIdx.x & 63;
    int p = blockIdx.x * 4 + wid;
    if (p >= npair) return;
    int b   = p / HW2;
    int rem = p - b * HW2;
    int py  = rem / 14;
    int px  = rem - py * 14;
    int row = lane >> 2;
    int c4  = lane & 3;
    const float4* src = (const float4*)(in + (size_t)b * IMG2
                                          + (size_t)(py * 16 + row) * IMG
                                          + px * 16) + c4;
    float4 v = *src;
    double s = (double)v.x + (double)v.y + (double)v.z + (double)v.w;
    #pragma unroll
    for (int off = 32; off; off >>= 1) s += __shfl_xor(s, off, 64);
    if (lane == 0) resized[p] = (float)(s * (1.0 / 256.0));
}

// ---------------- K2a: per-block min/max/sum partials ----------------
__global__ __launch_bounds__(256) void k_reduce1(const float* __restrict__ resized, int n4,
                                                 float* __restrict__ pmin,
                                                 float* __restrict__ pmax,
                                                 double* __restrict__ psum) {
    int g = blockIdx.x * 256 + threadIdx.x;
    float mn = INFINITY, mx = -INFINITY;
    double s = 0.0;
    if (g < n4) {
        float4 v = ((const float4*)resized)[g];
        mn = fminf(fminf(v.x, v.y), fminf(v.z, v.w));
        mx = fmaxf(fmaxf(v.x, v.y), fmaxf(v.z, v.w));
        s  = (double)v.x + (double)v.y + (double)v.z + (double)v.w;
    }
    #pragma unroll
    for (int off = 32; off; off >>= 1) {
        mn = fminf(mn, __shfl_xor(mn, off, 64));
        mx = fmaxf(mx, __shfl_xor(mx, off, 64));
        s += __shfl_xor(s, off, 64);
    }
    __shared__ float  smn[4], smx[4];
    __shared__ double ssm[4];
    int wid = threadIdx.x >> 6, lane = threadIdx.x & 63;
    if (lane == 0) { smn[wid] = mn; smx[wid] = mx; ssm[wid] = s; }
    __syncthreads();
    if (threadIdx.x == 0) {
        mn = fminf(fminf(smn[0], smn[1]), fminf(smn[2], smn[3]));
        mx = fmaxf(fmaxf(smx[0], smx[1]), fmaxf(smx[2], smx[3]));
        s  = ssm[0] + ssm[1] + ssm[2] + ssm[3];
        pmin[blockIdx.x] = mn; pmax[blockIdx.x] = mx; psum[blockIdx.x] = s;
    }
}

// ---------------- K2b: combine partials -> scalars {m_min, denom, scale} --------
__global__ __launch_bounds__(128) void k_reduce2(const float* __restrict__ pmin,
                                                 const float* __restrict__ pmax,
                                                 const double* __restrict__ psum,
                                                 int nblk, int ntot,
                                                 float* __restrict__ scalars) {
    int t = threadIdx.x;
    float mn = INFINITY, mx = -INFINITY;
    double s = 0.0;
    if (t < nblk) { mn = pmin[t]; mx = pmax[t]; s = psum[t]; }
    #pragma unroll
    for (int off = 32; off; off >>= 1) {
        mn = fminf(mn, __shfl_xor(mn, off, 64));
        mx = fmaxf(mx, __shfl_xor(mx, off, 64));
        s += __shfl_xor(s, off, 64);
    }
    __shared__ float  smn[2], smx[2];
    __shared__ double ssm[2];
    int wid = t >> 6, lane = t & 63;
    if (lane == 0) { smn[wid] = mn; smx[wid] = mx; ssm[wid] = s; }
    __syncthreads();
    if (t == 0) {
        mn = fminf(smn[0], smn[1]);
        mx = fmaxf(smx[0], smx[1]);
        s  = ssm[0] + ssm[1];
        // reference f32 semantics: denom = (m_max - m_min) + 1e-6 in f32
        float denom = __fadd_rn(__fsub_rn(mx, mn), 1e-6f);
        double mean     = s / (double)ntot;
        double avg_norm = (mean - (double)mn) / (double)denom;
        double cur_avg  = 0.25 + 0.75 * avg_norm;          // mean of compression_ratio
        float scale = (float)(0.5 / (cur_avg + 1e-6));
        scalars[0] = mn; scalars[1] = denom; scalars[2] = scale;
    }
}

// ---------------- K3: ratio / importance / merge mask ----------------
__global__ __launch_bounds__(256) void k_output(const float* __restrict__ resized,
                                                const float* __restrict__ scalars,
                                                float* __restrict__ out,
                                                int npair, int tpp, int num_tokens) {
    int base = blockIdx.x * 256;
    int g = base + threadIdx.x;
    float mn = scalars[0], denom = scalars[1], scale = scalars[2];
    __shared__ int      kk[256];
    __shared__ unsigned kbase[256];   // element offset of this pair's mask row
    int k = 0;
    unsigned kb = 0;
    if (g < npair) {
        float r    = resized[g];
        // emulate np elementwise f32 rounding: no fma contraction
        float norm   = __fdiv_rn(__fsub_rn(r, mn), denom);
        float ratio0 = __fadd_rn(0.25f, __fmul_rn(0.75f, norm));
        float sc     = __fmul_rn(ratio0, scale);
        float ratio  = fminf(fmaxf(sc, 0.25f), 1.0f);
        k = (int)rintf(__fmul_rn(ratio, (float)tpp));   // jnp.round = half-to-even
        k = min(max(k, 1), tpp);
        out[g]         = ratio;   // compression_ratio
        out[npair + g] = norm;    // importance_scores
        unsigned b = (unsigned)g / HW2;
        unsigned p = (unsigned)g - b * HW2;
        kb = b * (unsigned)num_tokens + p * (unsigned)tpp;
    }
    kk[threadIdx.x]    = k;
    kbase[threadIdx.x] = kb;
    __syncthreads();
    float* mask = out + 2 * (size_t)npair;
    int nprs  = min(256, npair - base);
    int total = nprs * tpp;
    for (int i = threadIdx.x; i < total; i += 256) {
        int pr = (unsigned)i / (unsigned)tpp;
        int wi = i - pr * tpp;
        mask[(size_t)kbase[pr] + wi] = (wi < kk[pr]) ? 1.0f : 0.0f;
    }
}

// ---------------- pad (only if 196*tpp < num_tokens; not hit at these sizes) ----
__global__ void k_pad(float* __restrict__ mask, int B, int num_tokens, int used) {
    int per = num_tokens - used;
    int idx = blockIdx.x * 256 + threadIdx.x;
    int tot = B * per;
    if (idx < tot) {
        int b = idx / per;
        int j = idx - b * per;
        mask[(size_t)b * num_tokens + used + j] = 0.0f;
    }
}

extern "C" void kernel_launch(void* const* d_in, const int* in_sizes, int n_in,
                              void* d_out, int out_size, void* d_ws, size_t ws_size,
                              hipStream_t stream) {
    const float* motion = (const float*)d_in[0];
    int nelem = in_sizes[0];                 // B*1*224*224
    int B     = nelem / IMG2;                // 512
    int npair = B * HW2;                     // 100352
    int num_tokens = (out_size - 2 * npair) / B;   // 6272
    int tpp   = num_tokens / HW2;            // 32

    // workspace layout
    float* resized = (float*)d_ws;
    size_t off = ((size_t)npair * sizeof(float) + 7) & ~(size_t)7;
    int n4   = npair / 4;                    // 25088 (196 % 4 == 0)
    int nblk = (n4 + 255) / 256;             // 98
    double* psum = (double*)((char*)d_ws + off);
    float*  pmin = (float*)(psum + nblk);
    float*  pmax = pmin + nblk;
    float*  scalars = pmax + nblk;

    int nb1 = (npair + 3) / 4;               // 25088 blocks, wave-per-patch x4
    hipLaunchKernelGGL(k_patch_mean, dim3(nb1), dim3(256), 0, stream,
                       motion, resized, npair);
    hipLaunchKernelGGL(k_reduce1, dim3(nblk), dim3(256), 0, stream,
                       resized, n4, pmin, pmax, psum);
    hipLaunchKernelGGL(k_reduce2, dim3(1), dim3(128), 0, stream,
                       pmin, pmax, psum, nblk, npair, scalars);
    int nb3 = (npair + 255) / 256;           // 392
    hipLaunchKernelGGL(k_output, dim3(nb3), dim3(256), 0, stream,
                       resized, scalars, (float*)d_out, npair, tpp, num_tokens);

    int used = HW2 * tpp;
    if (used < num_tokens) {
        int tot = B * (num_tokens - used);
        hipLaunchKernelGGL(k_pad, dim3((tot + 255) / 256), dim3(256), 0, stream,
                           (float*)d_out + 2 * (size_t)npair, B, num_tokens, used);
    }
}